// Round 12
// baseline (211.156 us; speedup 1.0000x reference)
//
#include <hip/hip_runtime.h>

#define D 128
#define BINCAP 6144
#define P2CAP 6144

typedef __attribute__((ext_vector_type(8))) short short8;
typedef __attribute__((ext_vector_type(4))) float f32x4;

__device__ inline unsigned short f2bf(float f) {
    unsigned u = __float_as_uint(f);
    return (unsigned short)((u + 0x7FFFu + ((u >> 16) & 1u)) >> 16);
}
__device__ inline float bflo(unsigned u) { return __uint_as_float(u << 16); }
__device__ inline float bfhi(unsigned u) { return __uint_as_float(u & 0xFFFF0000u); }

// ---------------------------------------------------------------- prep: p1 scatter (blocks 0..nb1-1) + W-pack (nb1..nb1+7)
// + pool-zero/bias (nb1+8). binCur memset to 0 beforehand; bin base t*BINCAP folded into delta.
__global__ __launch_bounds__(256) void k_prep(const int* __restrict__ row, const int* __restrict__ col, int E, int nb1,
                                              const float* __restrict__ w0, const float* __restrict__ w1,
                                              const float* __restrict__ b0, const float* __restrict__ b1,
                                              uint4* __restrict__ Wp0, uint4* __restrict__ Wp1,
                                              float* __restrict__ b0p, float* __restrict__ b1p,
                                              int* __restrict__ binCur, unsigned* __restrict__ ebuf,
                                              int* __restrict__ pool) {
    int b = blockIdx.x, t = threadIdx.x;
    if (b >= nb1) {
        int bb = b - nb1;
        if (bb < 8) {                               // W-pack: P1 position->col c(p) = (p&7)*16 + (p>>3)
            int e = bb * 256 + t;
            int l = e & 63, U = (e >> 6) & 7, T = e >> 9;
            int nn = U * 16 + (l & 15);
            int kq = T * 32 + ((l >> 4) << 3);
            unsigned r[4], s[4];
#pragma unroll
            for (int jj = 0; jj < 4; ++jj) {
                int k0 = kq + 2 * jj, k1 = k0 + 1;
                unsigned a0 = f2bf(w0[k0 * 128 + nn]), a1 = f2bf(w0[k1 * 128 + nn]);
                r[jj] = a0 | (a1 << 16);
                int c0 = ((k0 & 7) << 4) | (k0 >> 3), c1 = ((k1 & 7) << 4) | (k1 >> 3);
                unsigned q0 = f2bf(w1[c0 * 128 + nn]), q1 = f2bf(w1[c1 * 128 + nn]);
                s[jj] = q0 | (q1 << 16);
            }
            Wp0[e] = make_uint4(r[0], r[1], r[2], r[3]);
            Wp1[e] = make_uint4(s[0], s[1], s[2], s[3]);
        } else {
            for (int i = t; i < 64 * 128; i += 256) pool[i] = 0;
            if (t < 128) {
                int c = ((t & 7) << 4) | (t >> 3);
                b0p[t] = b0[c];
                b1p[t] = b1[c];
            }
        }
        return;
    }
    __shared__ int h[256], s[256], delta[256], lcur[256];
    __shared__ unsigned stage[4096];
    h[t] = 0;
    __syncthreads();
    int base = b * 4096;
    int cnt = min(4096, E - base);
    if (cnt == 4096) {
        int myc[16], myr[16];
        const int4* c4 = (const int4*)(col + base);
        const int4* r4 = (const int4*)(row + base);
#pragma unroll
        for (int k = 0; k < 4; ++k) {
            int4 cv = c4[t * 4 + k];
            int4 rv = r4[t * 4 + k];
            myc[k * 4 + 0] = cv.x; myc[k * 4 + 1] = cv.y; myc[k * 4 + 2] = cv.z; myc[k * 4 + 3] = cv.w;
            myr[k * 4 + 0] = rv.x; myr[k * 4 + 1] = rv.y; myr[k * 4 + 2] = rv.z; myr[k * 4 + 3] = rv.w;
        }
#pragma unroll
        for (int k = 0; k < 16; ++k) atomicAdd(&h[myc[k] >> 8], 1);
        __syncthreads();
        int v = h[t];
        s[t] = v;
        __syncthreads();
        for (int off = 1; off < 256; off <<= 1) {
            int tmp = (t >= off) ? s[t - off] : 0;
            __syncthreads();
            s[t] += tmp;
            __syncthreads();
        }
        int excl = s[t] - v;
        lcur[t] = excl;
        delta[t] = t * BINCAP + ((v > 0) ? atomicAdd(&binCur[t], v) : 0) - excl;
        __syncthreads();
#pragma unroll
        for (int k = 0; k < 16; ++k) {
            int d = myc[k];
            int slot = atomicAdd(&lcur[d >> 8], 1);
            stage[slot] = ((unsigned)d << 16) | (unsigned)myr[k];   // n < 2^16: both fit
        }
        __syncthreads();
#pragma unroll
        for (int k = 0; k < 16; ++k) {
            int slot = k * 256 + t;
            unsigned vv = stage[slot];
            ebuf[delta[vv >> 24] + slot] = vv;
        }
    } else {
        for (int k = 0; k < 16; ++k) {
            int e = base + k * 256 + t;
            if (e < E) atomicAdd(&h[col[e] >> 8], 1);
        }
        __syncthreads();
        int v = h[t];
        s[t] = v;
        __syncthreads();
        for (int off = 1; off < 256; off <<= 1) {
            int tmp = (t >= off) ? s[t - off] : 0;
            __syncthreads();
            s[t] += tmp;
            __syncthreads();
        }
        int excl = s[t] - v;
        lcur[t] = excl;
        delta[t] = t * BINCAP + ((v > 0) ? atomicAdd(&binCur[t], v) : 0) - excl;
        __syncthreads();
        for (int k = 0; k < 16; ++k) {
            int e = base + k * 256 + t;
            if (e < E) {
                int d = col[e];
                int slot = atomicAdd(&lcur[d >> 8], 1);
                stage[slot] = ((unsigned)d << 16) | (unsigned)row[e];
            }
        }
        __syncthreads();
        for (int k = 0; k < 16; ++k) {
            int slot = k * 256 + t;
            if (slot < cnt) {
                unsigned vv = stage[slot];
                ebuf[delta[vv >> 24] + slot] = vv;
            }
        }
    }
}

// ---------------------------------------------------------------- pass2: per-bin counting sort -> csr/off/end/dinv
__global__ __launch_bounds__(256) void k_p2sort(const unsigned* __restrict__ ebuf, const int* __restrict__ binCur,
                                                int* __restrict__ csr, int* __restrict__ off_, int* __restrict__ end_,
                                                float* __restrict__ dinv, int n) {
    __shared__ unsigned stage[P2CAP];
    __shared__ unsigned stage2[P2CAP];
    __shared__ int h[256], s[256], cur[256];
    int b = blockIdx.x, t = threadIdx.x;
    int beg = b * BINCAP;
    int cnt = binCur[b];
    h[t] = 0;
    __syncthreads();
    int nfull = cnt >> 2;
    const uint4* e4 = (const uint4*)(ebuf + beg);   // beg 16B aligned (BINCAP%4==0)
    uint4* st4 = (uint4*)stage;
    for (int i = t; i < nfull; i += 256) {
        uint4 v = e4[i];
        st4[i] = v;
        atomicAdd(&h[(v.x >> 16) & 0xFF], 1);
        atomicAdd(&h[(v.y >> 16) & 0xFF], 1);
        atomicAdd(&h[(v.z >> 16) & 0xFF], 1);
        atomicAdd(&h[(v.w >> 16) & 0xFF], 1);
    }
    for (int i = (nfull << 2) + t; i < cnt; i += 256) {
        unsigned v = ebuf[beg + i];
        stage[i] = v;
        atomicAdd(&h[(v >> 16) & 0xFF], 1);
    }
    __syncthreads();
    int v = h[t];
    s[t] = v;
    __syncthreads();
    for (int off = 1; off < 256; off <<= 1) {
        int tmp = (t >= off) ? s[t - off] : 0;
        __syncthreads();
        s[t] += tmp;
        __syncthreads();
    }
    int excl = s[t] - v;
    cur[t] = excl;
    int d = b * 256 + t;
    if (d < n) {
        off_[d] = beg + excl;
        end_[d] = beg + excl + v;
        dinv[d] = rsqrtf((float)(v + 1));           // +1 self-loop
    }
    __syncthreads();
    for (int i = t; i < cnt; i += 256) {
        unsigned vv = stage[i];
        int slot = atomicAdd(&cur[(vv >> 16) & 0xFF], 1);
        stage2[slot] = vv & 0xFFFFu;
    }
    __syncthreads();
    uint4* c4o = (uint4*)(csr + beg);
    uint4* st24 = (uint4*)stage2;
    for (int i = t; i < nfull; i += 256) c4o[i] = st24[i];
    for (int i = (nfull << 2) + t; i < cnt; i += 256) csr[beg + i] = (int)stage2[i];
}

// ---------------------------------------------------------------- MFMA GEMM, fp32 input (conv0), out bf16 P1 positions
__global__ __launch_bounds__(256) void k_gemm0(const float* __restrict__ x, const uint4* __restrict__ Wp,
                                               const float* __restrict__ dinv, unsigned* __restrict__ outb, int n) {
    int wave = threadIdx.x >> 6, l = threadIdx.x & 63;
    int mt = blockIdx.x * 4 + wave;
    int r0 = mt * 16;
    if (r0 >= n) return;
    int rowA = r0 + (l & 15);
    int kq = (l >> 4) * 8;
    f32x4 acc[8];
#pragma unroll
    for (int U = 0; U < 8; ++U) acc[U] = (f32x4){0.f, 0.f, 0.f, 0.f};
    const float* xr = x + (size_t)rowA * 128 + kq;
#pragma unroll
    for (int T = 0; T < 4; ++T) {
        float4 a0 = *(const float4*)(xr + T * 32);
        float4 a1 = *(const float4*)(xr + T * 32 + 4);
        short8 af;
        af[0] = (short)f2bf(a0.x); af[1] = (short)f2bf(a0.y);
        af[2] = (short)f2bf(a0.z); af[3] = (short)f2bf(a0.w);
        af[4] = (short)f2bf(a1.x); af[5] = (short)f2bf(a1.y);
        af[6] = (short)f2bf(a1.z); af[7] = (short)f2bf(a1.w);
#pragma unroll
        for (int U = 0; U < 8; ++U) {
            short8 bf = *(const short8*)&Wp[(T * 8 + U) * 64 + l];
            acc[U] = __builtin_amdgcn_mfma_f32_16x16x32_bf16(af, bf, acc[U], 0, 0, 0);
        }
    }
    int rq = l >> 4, cl = l & 15;
#pragma unroll
    for (int q = 0; q < 4; ++q) {
        int rr = r0 + rq * 4 + q;
        float d = dinv[rr];
        uint4 w;
        w.x = (unsigned)f2bf(acc[0][q] * d) | ((unsigned)f2bf(acc[1][q] * d) << 16);
        w.y = (unsigned)f2bf(acc[2][q] * d) | ((unsigned)f2bf(acc[3][q] * d) << 16);
        w.z = (unsigned)f2bf(acc[4][q] * d) | ((unsigned)f2bf(acc[5][q] * d) << 16);
        w.w = (unsigned)f2bf(acc[6][q] * d) | ((unsigned)f2bf(acc[7][q] * d) << 16);
        *(uint4*)(outb + (size_t)rr * 64 + cl * 4) = w;
    }
}

// ---------------------------------------------------------------- gather core: wave = 4 nodes, 16 lanes/node, dwordx4
__device__ inline void gather4(const uint4* __restrict__ hp4, const int* __restrict__ csr,
                               int q, int beg, int len, float acc[8]) {
    int maxlen = len;
    maxlen = max(maxlen, __shfl_xor(maxlen, 16, 64));
    maxlen = max(maxlen, __shfl_xor(maxlen, 32, 64));
    int j = 0;
    for (; j + 2 <= maxlen; j += 2) {
        bool a0 = (j < len), a1 = (j + 1 < len);
        int s0 = 0, s1 = 0;
        if (a0) s0 = csr[beg + j];
        if (a1) s1 = csr[beg + j + 1];
        uint4 u0, u1;
        if (a0) u0 = hp4[(size_t)s0 * 16 + q];
        if (a1) u1 = hp4[(size_t)s1 * 16 + q];
        if (a0) {
            acc[0] += bflo(u0.x); acc[1] += bfhi(u0.x);
            acc[2] += bflo(u0.y); acc[3] += bfhi(u0.y);
            acc[4] += bflo(u0.z); acc[5] += bfhi(u0.z);
            acc[6] += bflo(u0.w); acc[7] += bfhi(u0.w);
        }
        if (a1) {
            acc[0] += bflo(u1.x); acc[1] += bfhi(u1.x);
            acc[2] += bflo(u1.y); acc[3] += bfhi(u1.y);
            acc[4] += bflo(u1.z); acc[5] += bfhi(u1.z);
            acc[6] += bflo(u1.w); acc[7] += bfhi(u1.w);
        }
    }
    for (; j < maxlen; ++j) {
        if (j < len) {
            int s0 = csr[beg + j];
            uint4 u = hp4[(size_t)s0 * 16 + q];
            acc[0] += bflo(u.x); acc[1] += bfhi(u.x);
            acc[2] += bflo(u.y); acc[3] += bfhi(u.y);
            acc[4] += bflo(u.z); acc[5] += bfhi(u.z);
            acc[6] += bflo(u.w); acc[7] += bfhi(u.w);
        }
    }
}

// ---------------------------------------------------------------- fused agg(conv0) + GEMM(conv1)
__global__ __launch_bounds__(256) void k_aggemm(const unsigned* __restrict__ hp, const int* __restrict__ off_,
                                                const int* __restrict__ end_, const int* __restrict__ csr,
                                                const float* __restrict__ dinv, const float* __restrict__ bp,
                                                const uint4* __restrict__ Wp, unsigned* __restrict__ outb, int n) {
    __shared__ uint4 sA[16 * 17];
    int w = threadIdx.x >> 6, l = threadIdx.x & 63;
    int g = l >> 4, q = l & 15;
    int r0 = blockIdx.x * 16;
    int node = r0 + w * 4 + g;                  // n % 16 == 0
    const uint4* hp4 = (const uint4*)hp;
    float acc[8];
    uint4 us = hp4[(size_t)node * 16 + q];      // self-loop
    acc[0] = bflo(us.x); acc[1] = bfhi(us.x);
    acc[2] = bflo(us.y); acc[3] = bfhi(us.y);
    acc[4] = bflo(us.z); acc[5] = bfhi(us.z);
    acc[6] = bflo(us.w); acc[7] = bfhi(us.w);
    int beg = off_[node];
    int len = end_[node] - beg;
    gather4(hp4, csr, q, beg, len, acc);
    float d0 = dinv[node];
    const float4* bp4 = (const float4*)bp;
    float4 ba = bp4[q * 2], bb = bp4[q * 2 + 1];
    uint4 pk;
    pk.x = (unsigned)f2bf(fmaxf(fmaf(d0, acc[0], ba.x), 0.f)) | ((unsigned)f2bf(fmaxf(fmaf(d0, acc[1], ba.y), 0.f)) << 16);
    pk.y = (unsigned)f2bf(fmaxf(fmaf(d0, acc[2], ba.z), 0.f)) | ((unsigned)f2bf(fmaxf(fmaf(d0, acc[3], ba.w), 0.f)) << 16);
    pk.z = (unsigned)f2bf(fmaxf(fmaf(d0, acc[4], bb.x), 0.f)) | ((unsigned)f2bf(fmaxf(fmaf(d0, acc[5], bb.y), 0.f)) << 16);
    pk.w = (unsigned)f2bf(fmaxf(fmaf(d0, acc[6], bb.z), 0.f)) | ((unsigned)f2bf(fmaxf(fmaf(d0, acc[7], bb.w), 0.f)) << 16);
    sA[(w * 4 + g) * 17 + q] = pk;
    __syncthreads();
    int rq = l >> 4, cl = l & 15;
    f32x4 c0v = (f32x4){0.f, 0.f, 0.f, 0.f}, c1v = (f32x4){0.f, 0.f, 0.f, 0.f};
#pragma unroll
    for (int T = 0; T < 4; ++T) {
        short8 af = *(const short8*)&sA[(l & 15) * 17 + T * 4 + rq];
        short8 bf0 = *(const short8*)&Wp[(T * 8 + 2 * w) * 64 + l];
        short8 bf1 = *(const short8*)&Wp[(T * 8 + 2 * w + 1) * 64 + l];
        c0v = __builtin_amdgcn_mfma_f32_16x16x32_bf16(af, bf0, c0v, 0, 0, 0);
        c1v = __builtin_amdgcn_mfma_f32_16x16x32_bf16(af, bf1, c1v, 0, 0, 0);
    }
#pragma unroll
    for (int qq = 0; qq < 4; ++qq) {
        int rr = r0 + rq * 4 + qq;
        float d2 = dinv[rr];
        unsigned pkk = (unsigned)f2bf(c0v[qq] * d2) | ((unsigned)f2bf(c1v[qq] * d2) << 16);
        outb[(size_t)rr * 64 + cl * 4 + w] = pkk;
    }
}

// ---------------------------------------------------------------- agg conv1 + pool: barrier-free, wave-autonomous
// Wave = 4 nodes (batch-sorted). Segmented inclusive max-scan over groups via shfl_up; tails do atomicMax.
// Lane (g,q): v[k] is position 8q+k -> true col k*16+q.
__global__ __launch_bounds__(256) void k_agg1(const unsigned* __restrict__ hp, const int* __restrict__ off_,
                                              const int* __restrict__ end_, const int* __restrict__ csr,
                                              const float* __restrict__ dinv, const float* __restrict__ bp,
                                              const int* __restrict__ batch, int* __restrict__ pool, int n) {
    int w = threadIdx.x >> 6, l = threadIdx.x & 63;
    int g = l >> 4, q = l & 15;
    int node = blockIdx.x * 16 + w * 4 + g;     // n % 16 == 0
    const uint4* hp4 = (const uint4*)hp;
    float acc[8];
    uint4 us = hp4[(size_t)node * 16 + q];
    acc[0] = bflo(us.x); acc[1] = bfhi(us.x);
    acc[2] = bflo(us.y); acc[3] = bfhi(us.y);
    acc[4] = bflo(us.z); acc[5] = bfhi(us.z);
    acc[6] = bflo(us.w); acc[7] = bfhi(us.w);
    int beg = off_[node];
    int len = end_[node] - beg;
    gather4(hp4, csr, q, beg, len, acc);
    float d0 = dinv[node];
    const float4* bp4 = (const float4*)bp;
    float4 ba = bp4[q * 2], bb = bp4[q * 2 + 1];
    float v[8];
    v[0] = fmaxf(fmaf(d0, acc[0], ba.x), 0.f); v[1] = fmaxf(fmaf(d0, acc[1], ba.y), 0.f);
    v[2] = fmaxf(fmaf(d0, acc[2], ba.z), 0.f); v[3] = fmaxf(fmaf(d0, acc[3], ba.w), 0.f);
    v[4] = fmaxf(fmaf(d0, acc[4], bb.x), 0.f); v[5] = fmaxf(fmaf(d0, acc[5], bb.y), 0.f);
    v[6] = fmaxf(fmaf(d0, acc[6], bb.z), 0.f); v[7] = fmaxf(fmaf(d0, acc[7], bb.w), 0.f);
    int bid = batch[node];
    // segmented inclusive max-scan over groups g=0..3 (bids sorted within wave)
#pragma unroll
    for (int dshift = 16; dshift <= 32; dshift <<= 1) {
        int pb = __shfl_up(bid, dshift, 64);
        bool mrg = (l >= dshift) && (pb == bid);
#pragma unroll
        for (int k = 0; k < 8; ++k) {
            float pv = __shfl_up(v[k], dshift, 64);
            if (mrg) v[k] = fmaxf(v[k], pv);
        }
    }
    int nb_ = __shfl_down(bid, 16, 64);         // bid of group g+1
    bool tail = (g == 3) || (nb_ != bid);
    if (tail) {
#pragma unroll
        for (int k = 0; k < 8; ++k)
            atomicMax(&pool[bid * 128 + k * 16 + q], __float_as_int(v[k]));
    }
}

// ---------------------------------------------------------------- final MLP + log_softmax, 1 block/graph
__global__ __launch_bounds__(128) void k_mlp(const float* __restrict__ pool, const float* __restrict__ W0,
                                             const float* __restrict__ b0, const float* __restrict__ W1,
                                             const float* __restrict__ b1, float* __restrict__ out) {
    __shared__ float rowv[128];
    __shared__ float h2[128];
    __shared__ float h3[10];
    int g = blockIdx.x, t = threadIdx.x;
    rowv[t] = pool[g * 128 + t];
    __syncthreads();
    float acc = b0[t];
    for (int k = 0; k < 128; ++k) acc = fmaf(rowv[k], W0[k * 128 + t], acc);
    h2[t] = fmaxf(acc, 0.f);
    __syncthreads();
    if (t < 10) {
        float a = b1[t];
        for (int k = 0; k < 128; ++k) a = fmaf(h2[k], W1[k * 10 + t], a);
        h3[t] = fmaxf(a, 0.f);
    }
    __syncthreads();
    if (t == 0) {
        float mx = h3[0];
        for (int j = 1; j < 10; ++j) mx = fmaxf(mx, h3[j]);
        float s = 0.f;
        for (int j = 0; j < 10; ++j) s += expf(h3[j] - mx);
        float lse = logf(s) + mx;
        for (int j = 0; j < 10; ++j) out[g * 10 + j] = h3[j] - lse;
    }
}

// ----------------------------------------------------------------
extern "C" void kernel_launch(void* const* d_in, const int* in_sizes, int n_in,
                              void* d_out, int out_size, void* d_ws, size_t ws_size,
                              hipStream_t stream) {
    const float* x   = (const float*)d_in[0];
    const int* eidx  = (const int*)d_in[1];
    const int* batch = (const int*)d_in[2];
    const float* w0  = (const float*)d_in[3];
    const float* b0  = (const float*)d_in[4];
    const float* w1  = (const float*)d_in[5];
    const float* b1  = (const float*)d_in[6];
    const float* lw0 = (const float*)d_in[7];
    const float* lb0 = (const float*)d_in[8];
    const float* lw1 = (const float*)d_in[9];
    const float* lb1 = (const float*)d_in[10];
    float* out = (float*)d_out;

    int n = in_sizes[2];
    int E = in_sizes[1] / 2;
    const int* row = eidx;        // sources
    const int* col = eidx + E;    // destinations
    int nbins = (n + 255) >> 8;   // 196 (n < 2^16 required for packing)
    int nb1 = (E + 4095) / 4096;

    char* ws = (char*)d_ws;
    size_t o = 0;
    auto take = [&](size_t bytes) { void* p = ws + o; o += (bytes + 255) & ~(size_t)255; return p; };
    int*      binCur   = (int*)     take(256 * 4);
    int*      off_     = (int*)     take((size_t)n * 4);
    int*      end_     = (int*)     take((size_t)n * 4);
    float*    dinv     = (float*)   take((size_t)n * 4);
    int*      csr      = (int*)     take(((size_t)nbins * BINCAP + 64) * 4);
    unsigned* ebuf     = (unsigned*)take(((size_t)nbins * BINCAP + 64) * 4);
    uint4*    Wp0      = (uint4*)   take(2048 * 16);
    uint4*    Wp1      = (uint4*)   take(2048 * 16);
    float*    b0p      = (float*)   take(128 * 4);
    float*    b1p      = (float*)   take(128 * 4);
    unsigned* h0b      = (unsigned*)take((size_t)n * 64 * 4);   // bf16 P1 rows
    unsigned* h1b      = (unsigned*)take((size_t)n * 64 * 4);
    int*      pool     = (int*)     take(64 * 128 * 4);

    hipMemsetAsync(binCur, 0, 256 * 4, stream);
    k_prep<<<nb1 + 9, 256, 0, stream>>>(row, col, E, nb1, w0, w1, b0, b1,
                                        Wp0, Wp1, b0p, b1p, binCur, ebuf, pool);
    k_p2sort<<<nbins, 256, 0, stream>>>(ebuf, binCur, csr, off_, end_, dinv, n);

    int mtBlocks = ((n + 15) / 16 + 3) / 4;

    k_gemm0<<<mtBlocks, 256, 0, stream>>>(x, Wp0, dinv, h0b, n);
    k_aggemm<<<n / 16, 256, 0, stream>>>(h0b, off_, end_, csr, dinv, b0p, Wp1, h1b, n);
    k_agg1<<<n / 16, 256, 0, stream>>>(h1b, off_, end_, csr, dinv, b1p, batch, pool, n);
    k_mlp<<<64, 128, 0, stream>>>((const float*)pool, lw0, lb0, lw1, lb1, out);
}